// Round 15
// baseline (861.560 us; speedup 1.0000x reference)
//
#include <hip/hip_runtime.h>
#include <hip/hip_bf16.h>

typedef __hip_bfloat16 bf16;
typedef unsigned short u16;
typedef __attribute__((ext_vector_type(8))) short s16x8;
typedef __attribute__((ext_vector_type(4))) short s16x4;
typedef __attribute__((ext_vector_type(4))) float f32x4;

#define EXP 3
#define BB  4
#define LL  1024
#define DD  768
#define DSN 64
#define DIN 1536
#define DTR 48
#define MM  4096       // B*L rows per expert

struct alignas(8)  bf16x4 { bf16 v[4]; };
struct alignas(16) bf16x8 { bf16 v[8]; };

__device__ __forceinline__ float siluf(float x) { return x / (1.f + __expf(-x)); }
__device__ __forceinline__ float bf2f(u16 h) { union { unsigned u; float f; } x; x.u = ((unsigned)h) << 16; return x.f; }

// fast softplus: ln(1+e^x) = max(x,0) + ln2*log2(1+exp2(-|x|*log2e)); raw
// v_exp_f32/v_log_f32, no libm. bf16 output -> precision ample.
__device__ __forceinline__ float softplusf(float x) {
  const float LOG2E = 1.44269504088896f, LN2 = 0.69314718055995f;
  float t = __builtin_amdgcn_exp2f(-fabsf(x) * LOG2E);
  return fmaxf(x, 0.f) + LN2 * __builtin_amdgcn_logf(1.f + t);
}

// elementwise bf16 product of two packed 8-vectors (f32 math, RNE back)
__device__ __forceinline__ s16x8 gmul8(s16x8 a, s16x8 g) {
  s16x8 r;
#pragma unroll
  for (int j = 0; j < 8; j++) {
    union { bf16 b; u16 u; } cv;
    cv.b = (bf16)(bf2f((u16)a[j]) * bf2f((u16)g[j]));
    r[j] = (short)cv.u;
  }
  return r;
}

// DPP row-rotate add; rotate-allreduce {8,4,2,1} -> full 16-lane sum in every lane.
template <int CTRL>
__device__ __forceinline__ float ror_add(float x) {
  int y = __builtin_amdgcn_update_dpp(0, __float_as_int(x), CTRL, 0xf, 0xf, true);
  return x + __int_as_float(y);
}

// ---------------- LayerNorm apply + bf16 convert: per_ch -> Abf ----------------
__launch_bounds__(256)
__global__ void ln_apply_k(const float* __restrict__ pc, const float* __restrict__ lng,
                           const float* __restrict__ lnb, bf16* __restrict__ out) {
  int row  = blockIdx.x * 4 + (threadIdx.x >> 6);
  int lane = threadIdx.x & 63;
  const float* x = pc + (size_t)row * DD;
  float4 v[3];
  float s = 0.f, sq = 0.f;
#pragma unroll
  for (int i = 0; i < 3; i++) {
    v[i] = *(const float4*)(x + lane * 4 + i * 256);
    s  += v[i].x + v[i].y + v[i].z + v[i].w;
    sq += v[i].x * v[i].x + v[i].y * v[i].y + v[i].z * v[i].z + v[i].w * v[i].w;
  }
#pragma unroll
  for (int o = 1; o < 64; o <<= 1) { s += __shfl_xor(s, o); sq += __shfl_xor(sq, o); }
  float mu = s * (1.f / 768.f);
  float rs = rsqrtf(sq * (1.f / 768.f) - mu * mu + 1e-5f);
  bf16* op = out + (size_t)row * DD;
#pragma unroll
  for (int i = 0; i < 3; i++) {
    int col = lane * 4 + i * 256;
    float4 g4 = *(const float4*)(lng + col);
    float4 b4 = *(const float4*)(lnb + col);
    bf16x4 pk;
    pk.v[0] = (bf16)((v[i].x - mu) * rs * g4.x + b4.x);
    pk.v[1] = (bf16)((v[i].y - mu) * rs * g4.y + b4.y);
    pk.v[2] = (bf16)((v[i].z - mu) * rs * g4.z + b4.z);
    pk.v[3] = (bf16)((v[i].w - mu) * rs * g4.w + b4.w);
    *(bf16x4*)(op + col) = pk;
  }
}

// ---------------- transpose + f32->bf16 weight conversion ----------------
__launch_bounds__(256)
__global__ void tcvt_k(const float* __restrict__ in, bf16* __restrict__ out,
                       int Ksrc, int ldin, int ldout,
                       size_t sIn, size_t sOut, int mode, const float* __restrict__ alphap) {
  __shared__ float tl[32][33];
  int z = blockIdx.z;
  const float* src = in + (size_t)z * sIn;
  bf16* dst = out + (size_t)z * sOut;
  int n0 = blockIdx.x * 32, k0 = blockIdx.y * 32;
  int tx = threadIdx.x, ty = threadIdx.y;
  int n = n0 + tx;
  int c = n; bool nv = true;
  if (mode == 1) {
    if (n < 48)       c = n;
    else if (n < 64)  nv = false;
    else if (n < 192) c = n - 16;
    else              nv = false;
  }
  float scale = 1.f;
  if (mode == 2) {
    float a0 = alphap[0], a1 = alphap[1], a2 = alphap[2];
    float mx = fmaxf(a0, fmaxf(a1, a2));
    float e0 = __expf(a0 - mx), e1 = __expf(a1 - mx), e2 = __expf(a2 - mx);
    scale = ((z == 0) ? e0 : (z == 1) ? e1 : e2) / (e0 + e1 + e2);
  }
#pragma unroll
  for (int i = 0; i < 32; i += 8) {
    int k = k0 + ty + i;
    float v = (nv && k < Ksrc) ? src[(size_t)k * ldin + c] : 0.f;
    tl[ty + i][tx] = v * scale;
  }
  __syncthreads();
#pragma unroll
  for (int i = 0; i < 32; i += 8) {
    dst[(size_t)(n0 + ty + i) * ldout + (k0 + tx)] = (bf16)tl[tx][ty + i];
  }
}

// ---------------- causal depthwise conv (K=4) + SiLU, 8 channels/thread ----------------
__launch_bounds__(256)
__global__ void conv_silu_k(const bf16* __restrict__ xp, const float* __restrict__ cw,
                            const float* __restrict__ cb, bf16* __restrict__ xs) {
  long i = ((long)blockIdx.x * 256 + threadIdx.x) * 8;   // elem index, 8 channels
  int  c  = (int)(i % DIN);
  long rl = i / DIN;                                     // (e*B + b)*L + l
  int  l  = (int)(rl & (LL - 1));
  int  e  = (int)(rl >> 12);                             // B*L = 4096
  const float* wp  = cw + (size_t)e * DIN * 4 + (size_t)c * 4;
  const float* cbp = cb + (size_t)e * DIN + c;
  float acc[8];
#pragma unroll
  for (int j = 0; j < 8; j++) acc[j] = cbp[j];
#pragma unroll
  for (int tap = 0; tap < 4; tap++) {
    if (l - 3 + tap >= 0) {
      s16x8 xv = *(const s16x8*)(const void*)(xp + (rl + tap - 3) * DIN + c);
#pragma unroll
      for (int j = 0; j < 8; j++)
        acc[j] = fmaf(bf2f((u16)xv[j]), wp[j * 4 + tap], acc[j]);
    }
  }
  bf16x8 pk;
#pragma unroll
  for (int j = 0; j < 8; j++) pk.v[j] = (bf16)siluf(acc[j]);
  *(bf16x8*)(xs + rl * DIN + c) = pk;
}

// ---------------- bf16 MFMA GEMM, 128x128 tile, BK=32 (R5 measured-best body) ----------------
// MODE 0: xz GEMM  -> o0=xp bf16 (n<DIN), o1=silu(z) bf16
// MODE 1: dbl GEMM -> gc<64 -> dblp bf16 (ld 64); gc 64..191 -> dblf f32 [M][128]
// MODE 2: dt GEMM  -> o0=softplus(acc + bias[gc]) bf16 (row-major [M][DIN])
// MODE 3: COMBINED out GEMM over K = EXP*DIN (expert = k/DIN): A = y (gated by
//         gat at load), B^T = WoutT (pre-scaled by softmax(alpha)); epilogue
//         outp = bias(=base) + acc. No atomics, single pass, z unused.
template<int MODE>
__launch_bounds__(256)
__global__ void mfma_gemm_k(const bf16* __restrict__ A, const bf16* __restrict__ Bt,
                            int Kdim, int lda,
                            size_t sA, size_t sB, size_t sO,
                            bf16* __restrict__ o0, bf16* __restrict__ o1,
                            const float* __restrict__ bias,
                            float* __restrict__ outp,
                            const bf16* __restrict__ gat) {
  __shared__ short As[128 * 32];
  __shared__ short Bs[128 * 32];
  int z = blockIdx.z;
  if constexpr (MODE != 3) {
    A  += (size_t)z * sA;
    Bt += (size_t)z * sB;
  }
  if (o0) o0 += (size_t)z * sO;
  if (o1) o1 += (size_t)z * sO;
  if constexpr (MODE == 1) outp += (size_t)z * (size_t)MM * 128;
  const float* bz = (MODE == 2) ? bias + (size_t)z * DIN : bias;

  int t = threadIdx.x;
  int l = t & 63, w = t >> 6;
  int wr = w >> 1, wc = w & 1;
  int n0 = blockIdx.x * 128, r0 = blockIdx.y * 128;

  int row = t >> 2, c3 = t & 3, col = c3 * 8;
  int plo = ((c3 & 1) ? 16 : 0) + ((c3 & 2) ? 4 : 0);   // k-permuted LDS slot
  int lrow = (l & 15) * 32 + (l >> 4) * 8;

  f32x4 acc[4][4] = {};

  for (int k0 = 0; k0 < Kdim; k0 += 32) {
    const bf16 *pa, *pb;
    if constexpr (MODE == 3) {
      int e  = k0 / DIN;           // expert of this k-panel (panel never crosses)
      int kk = k0 - e * DIN;
      pa = A  + (size_t)e * sA + (size_t)(r0 + row) * lda + kk + col;
      pb = Bt + (size_t)e * sB + (size_t)(n0 + row) * DIN + kk + col;
    } else {
      pa = A  + (size_t)(r0 + row) * lda  + k0 + col;
      pb = Bt + (size_t)(n0 + row) * Kdim + k0 + col;
    }
    s16x8 va0 = *(const s16x8*)(const void*)(pa);
    s16x8 va1 = *(const s16x8*)(const void*)(pa + (size_t)64 * lda);
    s16x8 vb0 = *(const s16x8*)(const void*)(pb);
    s16x8 vb1 = *(const s16x8*)(const void*)(pb + (size_t)64 * ((MODE == 3) ? DIN : Kdim));
    if constexpr (MODE == 3) {   // gate y*g at load (gat has A's layout)
      const bf16* pg = gat + (pa - A);
      va0 = gmul8(va0, *(const s16x8*)(const void*)(pg));
      va1 = gmul8(va1, *(const s16x8*)(const void*)(pg + (size_t)64 * lda));
    }
    __syncthreads();   // previous iteration's ds_reads done
    *(s16x4*)(As + row * 32 + plo)          = __builtin_shufflevector(va0, va0, 0, 1, 2, 3);
    *(s16x4*)(As + row * 32 + plo + 8)      = __builtin_shufflevector(va0, va0, 4, 5, 6, 7);
    *(s16x4*)(As + (row + 64) * 32 + plo)     = __builtin_shufflevector(va1, va1, 0, 1, 2, 3);
    *(s16x4*)(As + (row + 64) * 32 + plo + 8) = __builtin_shufflevector(va1, va1, 4, 5, 6, 7);
    *(s16x4*)(Bs + row * 32 + plo)          = __builtin_shufflevector(vb0, vb0, 0, 1, 2, 3);
    *(s16x4*)(Bs + row * 32 + plo + 8)      = __builtin_shufflevector(vb0, vb0, 4, 5, 6, 7);
    *(s16x4*)(Bs + (row + 64) * 32 + plo)     = __builtin_shufflevector(vb1, vb1, 0, 1, 2, 3);
    *(s16x4*)(Bs + (row + 64) * 32 + plo + 8) = __builtin_shufflevector(vb1, vb1, 4, 5, 6, 7);
    __syncthreads();
    s16x8 af[4], bfv[4];
#pragma unroll
    for (int m = 0; m < 4; m++) af[m]  = *(const s16x8*)(As + (wr * 64 + m * 16) * 32 + lrow);
#pragma unroll
    for (int n = 0; n < 4; n++) bfv[n] = *(const s16x8*)(Bs + (wc * 64 + n * 16) * 32 + lrow);
#pragma unroll
    for (int m = 0; m < 4; m++)
#pragma unroll
      for (int n = 0; n < 4; n++)
        acc[m][n] = __builtin_amdgcn_mfma_f32_16x16x32_bf16(af[m], bfv[n], acc[m][n], 0, 0, 0);
  }

  int rb = r0 + wr * 64 + ((l >> 4) << 2);
  int cb = n0 + wc * 64 + (l & 15);
#pragma unroll
  for (int m = 0; m < 4; m++)
#pragma unroll
    for (int n = 0; n < 4; n++)
#pragma unroll
      for (int r = 0; r < 4; r++) {
        int gr = rb + m * 16 + r;
        int gc = cb + n * 16;
        float v = acc[m][n][r];
        if constexpr (MODE == 0) {
          if (n0 < DIN) o0[(size_t)gr * DIN + gc] = (bf16)v;
          else          o1[(size_t)gr * DIN + (gc - DIN)] = (bf16)siluf(v);
        } else if constexpr (MODE == 1) {
          if (gc < 64)       o0[(size_t)gr * 64 + gc] = (bf16)v;
          else if (gc < 192) outp[(size_t)gr * 128 + (gc - 64)] = v;
        } else if constexpr (MODE == 2) {
          o0[(size_t)gr * DIN + gc] = (bf16)softplusf(v + bz[gc]);
        } else {
          size_t o = (size_t)gr * DD + gc;
          outp[o] = bias[o] + v;     // out = base + sum_e (y*g) @ (w_e*W_out)
        }
      }
}

// ---------------- selective scan: 16 lanes/channel, 4 states/lane ----------------
// Measured-best structure (445 us, 66% VALUBusy, VGPR 24): f32 B/C row-major,
// DPP rotate-allreduce, raw v_exp_f32, 32-bit offsets, depth-1 full prefetch
// + unroll 4; stores UNGATED y (gate applied in MODE3 A-staging).
__launch_bounds__(256)
__global__ void scan_k(const bf16* __restrict__ dtb, bf16* __restrict__ xsb,
                       const float* __restrict__ dbl,
                       const float* __restrict__ A_log, const float* __restrict__ Dsk) {
  int gt = blockIdx.x * 256 + threadIdx.x;
  int sg = gt & 15;             // states [sg*4, sg*4+4)
  int cidx = gt >> 4;           // (e*B + b)*DIN + d
  int d  = cidx % DIN;
  int eb = cidx / DIN;
  int e  = eb >> 2;             // B == 4

  float4 Ar = *(const float4*)(A_log + ((size_t)e * DIN + d) * DSN + sg * 4);
  const float LOG2E = 1.44269504088896f;
  float4 A2;
  A2.x = -__expf(Ar.x) * LOG2E;
  A2.y = -__expf(Ar.y) * LOG2E;
  A2.z = -__expf(Ar.z) * LOG2E;
  A2.w = -__expf(Ar.w) * LOG2E;
  float4 h = {0.f, 0.f, 0.f, 0.f};
  float dskip = Dsk[(size_t)e * DIN + d];

  unsigned idx  = (unsigned)eb * (LL * DIN) + (unsigned)d;   // bf16 elem offset
  unsigned bofs = (unsigned)eb * (LL * 128) + (unsigned)(sg * 4);

  // prefetch l = 0  (final iteration prefetches 1 row past this (e,b) slice;
  // lands in the next ws region, value unused -- safe)
  float dtv = (float)dtb[idx];
  float u   = (float)xsb[idx];
  float4 Bv = *(const float4*)(dbl + bofs);
  float4 Cv = *(const float4*)(dbl + bofs + 64);

#pragma unroll 4
  for (int l = 0; l < LL; ++l) {
    unsigned idxn = idx + DIN;
    unsigned bofn = bofs + 128;
    float dtn = (float)dtb[idxn];
    float un  = (float)xsb[idxn];
    float4 Bn = *(const float4*)(dbl + bofn);
    float4 Cn = *(const float4*)(dbl + bofn + 64);

    float du = dtv * u;
    float4 dA;
    dA.x = __builtin_amdgcn_exp2f(dtv * A2.x);
    dA.y = __builtin_amdgcn_exp2f(dtv * A2.y);
    dA.z = __builtin_amdgcn_exp2f(dtv * A2.z);
    dA.w = __builtin_amdgcn_exp2f(dtv * A2.w);
    h.x = fmaf(dA.x, h.x, du * Bv.x);
    h.y = fmaf(dA.y, h.y, du * Bv.y);
    h.z = fmaf(dA.z, h.z, du * Bv.z);
    h.w = fmaf(dA.w, h.w, du * Bv.w);
    float p = fmaf(h.x, Cv.x, fmaf(h.y, Cv.y, fmaf(h.z, Cv.z, h.w * Cv.w)));
    p = ror_add<0x128>(p);   // row_ror:8
    p = ror_add<0x124>(p);   // row_ror:4
    p = ror_add<0x122>(p);   // row_ror:2
    p = ror_add<0x121>(p);   // row_ror:1
    if (sg == 0) {
      xsb[idx] = (bf16)fmaf(u, dskip, p);   // UNGATED y over xs
    }
    idx = idxn; bofs = bofn;
    dtv = dtn; u = un; Bv = Bn; Cv = Cn;
  }
}

extern "C" void kernel_launch(void* const* d_in, const int* in_sizes, int n_in,
                              void* d_out, int out_size, void* d_ws, size_t ws_size,
                              hipStream_t stream) {
  const float* base   = (const float*)d_in[0];
  const float* per_ch = (const float*)d_in[1];
  const float* alpha  = (const float*)d_in[2];
  const float* ln_g   = (const float*)d_in[3];
  const float* ln_b   = (const float*)d_in[4];
  const float* W_in   = (const float*)d_in[5];
  const float* conv_w = (const float*)d_in[6];
  const float* conv_b = (const float*)d_in[7];
  const float* W_x    = (const float*)d_in[8];
  const float* W_dt   = (const float*)d_in[9];
  const float* b_dt   = (const float*)d_in[10];
  const float* A_log  = (const float*)d_in[11];
  const float* D_skip = (const float*)d_in[12];
  const float* W_out  = (const float*)d_in[13];
  float* out = (float*)d_out;
  (void)in_sizes; (void)n_in; (void)out_size; (void)ws_size;

  // Workspace layout (131.9 MB), lifetime overlays:
  //  R1 [37.75M]: Abf (18.87M) -> xs (row-major) -> UNGATED y (scan in-place)
  //  R2 [37.75M]: g = silu(z)  (consumed by MODE3 staging)
  //  R3 [37.75M]: xp -> dt (row-major [M][DIN])
  //  R4 [14.16M]: W_inT -> [WoutT 7.08M | dblf f32 row-major [E*M][128] 6.29M]
  //  R5 [ 2.36M]: W_xT ;  R6 [0.59M]: W_dtT ;  R7 [1.57M]: dblp bf16 (ld 64)
  char* ws = (char*)d_ws;
  const size_t R = (size_t)EXP * MM * DIN * 2;            // 37,748,736
  bf16* Abf   = (bf16*)ws;
  bf16* xsws  = (bf16*)ws;
  bf16* gws   = (bf16*)(ws + R);
  bf16* dtws  = (bf16*)(ws + 2 * R);
  char* R4    = ws + 3 * R;
  bf16*  WinT  = (bf16*)R4;
  bf16*  WoutT = (bf16*)R4;                               // overlays WinT after MODE0
  float* dblf  = (float*)(R4 + 7077888);                  // E*M*128 f32 = 6.29M
  bf16* WxT   = (bf16*)(ws + 3 * R + 14155776);
  bf16* WdtT  = (bf16*)(ws + 3 * R + 14155776 + 2359296);
  bf16* dblp  = (bf16*)(ws + 3 * R + 14155776 + 2359296 + 589824);

  dim3 blk2(32, 8);

  // prep: LN->bf16, weight transposes (bf16, B^T layout)
  ln_apply_k<<<EXP * BB * LL / 4, 256, 0, stream>>>(per_ch, ln_g, ln_b, Abf);
  tcvt_k<<<dim3(96, 24, EXP), blk2, 0, stream>>>(W_in, WinT, 768, 3072, 768,
        (size_t)768 * 3072, (size_t)3072 * 768, 0, nullptr);
  tcvt_k<<<dim3(8, 48, EXP), blk2, 0, stream>>>(W_x, WxT, 1536, 176, 1536,
        (size_t)1536 * 176, (size_t)256 * 1536, 1, nullptr);
  tcvt_k<<<dim3(48, 2, EXP), blk2, 0, stream>>>(W_dt, WdtT, 48, 1536, 64,
        (size_t)48 * 1536, (size_t)1536 * 64, 0, nullptr);

  // xz = Abf @ W_in -> xp (dtws), silu(z) (gws)
  mfma_gemm_k<0><<<dim3(24, 32, EXP), 256, 0, stream>>>(Abf, WinT, 768, DD,
        (size_t)MM * DD, (size_t)3072 * 768, (size_t)MM * DIN,
        dtws, gws, nullptr, nullptr, nullptr);

  // W_outT (pre-scaled by softmax(alpha)) -- overlays W_inT, safe after MODE0
  tcvt_k<<<dim3(24, 48, EXP), blk2, 0, stream>>>(W_out, WoutT, 1536, 768, 1536,
        (size_t)1536 * 768, (size_t)768 * 1536, 2, alpha);

  // causal conv + silu -> xs (overlays Abf, safe after MODE0)
  conv_silu_k<<<EXP * BB * LL * DIN / 8 / 256, 256, 0, stream>>>(dtws, conv_w, conv_b, xsws);

  // dbl = xs @ W_x: dt cols -> dblp (bf16, ld 64); B|C -> dblf f32 row-major [M][128]
  mfma_gemm_k<1><<<dim3(2, 32, EXP), 256, 0, stream>>>(xsws, WxT, 1536, DIN,
        (size_t)MM * DIN, (size_t)256 * 1536, (size_t)MM * 64,
        dblp, nullptr, nullptr, dblf, nullptr);

  // dt = softplus(dblp @ W_dt + b_dt) -> dtws
  mfma_gemm_k<2><<<dim3(12, 32, EXP), 256, 0, stream>>>(dblp, WdtT, 64, 64,
        (size_t)MM * 64, (size_t)1536 * 64, (size_t)MM * DIN,
        dtws, nullptr, b_dt, nullptr, nullptr);

  // scan (ungated y, in place over xs)
  scan_k<<<EXP * BB * DIN * 16 / 256, 256, 0, stream>>>(dtws, xsws, dblf, A_log, D_skip);

  // out = base + sum_e (y*g)_e @ (w_e*W_out_e): ONE combined-K GEMM (K=4608),
  // no atomics, no copy4 init.
  mfma_gemm_k<3><<<dim3(6, 32, 1), 256, 0, stream>>>(xsws, WoutT, EXP * DIN, DIN,
        (size_t)MM * DIN, (size_t)768 * 1536, 0,
        nullptr, nullptr, base, out, gws);
}